// Round 10
// baseline (321.928 us; speedup 1.0000x reference)
//
#include <hip/hip_runtime.h>
#include <hip/hip_bf16.h>
#include <cstdint>
#include <cstddef>

#define D_MODEL 1024
#define N_HEAD 16
#define HEAD_DIM 64
#define BATCH 4
#define SEQ 2048
#define M_ROWS (BATCH * SEQ) // 8192

typedef __attribute__((ext_vector_type(8))) short short8v;  // 8 bf16 (4 VGPRs)
typedef __attribute__((ext_vector_type(4))) float f32x4;    // MFMA 16x16 C/D
typedef __attribute__((ext_vector_type(16))) float f32x16;  // MFMA 32x32 C/D

// ---------- bf16 helpers ----------
__device__ __forceinline__ unsigned short f2bf(float f) { // RNE
    union { uint32_t i; float f; } c;
    c.f = f;
    uint32_t r = c.i + 0x7FFFu + ((c.i >> 16) & 1u);
    return (unsigned short)(r >> 16);
}
__device__ __forceinline__ unsigned short trunc_bf(float f) { // truncation
    return (unsigned short)(__float_as_uint(f) >> 16);
}
// pack hi16 of two fp32 into one dword: lo<-a, hi<-b (truncation)
__device__ __forceinline__ uint32_t pack_trunc2(float a, float b) {
    return __builtin_amdgcn_perm(__float_as_uint(b), __float_as_uint(a), 0x07060302u);
}
// pack two fp32 -> dword of 2 bf16 with RNE
__device__ __forceinline__ uint32_t pack_rne2(float a, float b) {
    return (uint32_t)f2bf(a) | ((uint32_t)f2bf(b) << 16);
}

struct __align__(16) U4 { uint32_t x, y, z, w; };
struct __align__(8) U2 { uint32_t x, y; };

// swizzled LDS offset (elements) within a 64-wide bank:
// row*64 + (8-elem group XOR low row bits)*8
__device__ __forceinline__ int sw_off(int row, int gl) {
    return row * 64 + ((gl ^ (row & 7)) << 3);
}

// async global->LDS, 16B per lane; LDS dest = wave-uniform base + lane*16
__device__ __forceinline__ void gload16(const unsigned short *g, unsigned short *l) {
    __builtin_amdgcn_global_load_lds((const __attribute__((address_space(1))) void *)g,
                                     (__attribute__((address_space(3))) void *)l, 16, 0, 0);
}

// ---------------------------------------------------------------------------
// fp32 -> bf16 convert (truncation, matches in-staging numerics)
// ---------------------------------------------------------------------------
__global__ __launch_bounds__(256)
void cvt_kernel(const float *__restrict__ src, unsigned short *__restrict__ dst)
{
    const size_t i = ((size_t)blockIdx.x * 256 + threadIdx.x) * 8;
    float4 lo = *(const float4 *)(src + i);
    float4 hi = *(const float4 *)(src + i + 4);
    U4 pk;
    pk.x = pack_trunc2(lo.x, lo.y);
    pk.y = pack_trunc2(lo.z, lo.w);
    pk.z = pack_trunc2(hi.x, hi.y);
    pk.w = pack_trunc2(hi.z, hi.w);
    *(U4 *)(dst + i) = pk;
}

// ---------------------------------------------------------------------------
// Weight transpose+convert: W[1024][1024] fp32 row-major -> Wt[n][k] bf16.
// ---------------------------------------------------------------------------
__global__ __launch_bounds__(256)
void wtrans_kernel(const float *__restrict__ W, unsigned short *__restrict__ Wt)
{
    __shared__ float tile[32][33];
    const int t = threadIdx.x;
    const int tx = t & 31, ty = t >> 5; // ty 0..7
    const int bk = blockIdx.y * 32, bn = blockIdx.x * 32;
#pragma unroll
    for (int i = 0; i < 4; i++)
        tile[ty + 8 * i][tx] = W[(size_t)(bk + ty + 8 * i) * D_MODEL + bn + tx];
    __syncthreads();
#pragma unroll
    for (int i = 0; i < 4; i++)
        Wt[(size_t)(bn + ty + 8 * i) * D_MODEL + bk + tx] = trunc_bf(tile[tx][ty + 8 * i]);
}

// ---------------------------------------------------------------------------
// Fused Q+K projection GEMM. blockIdx.z: 0 -> Q (escale), 1 -> K.
// 128x128 tile, BK=64, grid (64,8,2) = 1024 blocks -> 4 blocks/CU
// (launch_bounds(256,4)); co-resident blocks interleave stage-wait and MFMA
// (m114 TLP mechanism that powers m97's 874 TF). 2 Wt = 4 MB -> L2-fits/XCD.
// ---------------------------------------------------------------------------
__global__ __launch_bounds__(256, 4)
void qk_gemm_kernel(const unsigned short *__restrict__ cq,
                    const unsigned short *__restrict__ ckb,
                    const unsigned short *__restrict__ wt2, // [2][1024][1024]
                    const float *__restrict__ bq, const float *__restrict__ bk,
                    unsigned short *__restrict__ oq, unsigned short *__restrict__ ok,
                    float qscale)
{
    __shared__ __align__(16) unsigned short At[128 * 64];
    __shared__ __align__(16) unsigned short Bt[128 * 64];

    const int z = blockIdx.z;
    const unsigned short *A = z ? ckb : cq;
    const unsigned short *Wt = wt2 + (size_t)z * D_MODEL * D_MODEL;
    const float *bias = z ? bk : bq;
    unsigned short *out = z ? ok : oq;
    const float es = z ? 1.f : qscale;

    const int t = threadIdx.x;
    const int wave = t >> 6;
    const int lane = t & 63;
    const int n_ = lane & 15;
    const int quad = lane >> 4;
    const int wm = wave >> 1, wn = wave & 1;
    const int m0 = blockIdx.x * 128;
    const int n0 = blockIdx.y * 128;

    f32x4 acc[4][4];
#pragma unroll
    for (int i = 0; i < 4; i++)
#pragma unroll
        for (int j = 0; j < 4; j++) acc[i][j] = (f32x4){0.f, 0.f, 0.f, 0.f};

    const int rl = lane >> 3;        // gload sub-row 0..7
    const int gsw = (lane & 7) ^ rl; // gload inverse-swizzled col group

    for (int k0 = 0; k0 < D_MODEL; k0 += 64) {
        __syncthreads();
#pragma unroll
        for (int c = 0; c < 4; c++) {
            const int rb = wave * 32 + c * 8;
            gload16(A + (size_t)(m0 + rb + rl) * D_MODEL + k0 + (gsw << 3), &At[rb * 64]);
            gload16(Wt + (size_t)(n0 + rb + rl) * D_MODEL + k0 + (gsw << 3), &Bt[rb * 64]);
        }
        __syncthreads();

#pragma unroll
        for (int c = 0; c < 2; c++) {
            short8v af[4], bf[4];
#pragma unroll
            for (int mt = 0; mt < 4; mt++)
                af[mt] = *(const short8v *)&At[sw_off(wm * 64 + mt * 16 + n_, c * 4 + quad)];
#pragma unroll
            for (int nt = 0; nt < 4; nt++)
                bf[nt] = *(const short8v *)&Bt[sw_off(wn * 64 + nt * 16 + n_, c * 4 + quad)];
#pragma unroll
            for (int mt = 0; mt < 4; mt++)
#pragma unroll
                for (int nt = 0; nt < 4; nt++)
                    acc[mt][nt] = __builtin_amdgcn_mfma_f32_16x16x32_bf16(
                        af[mt], bf[nt], acc[mt][nt], 0, 0, 0);
        }
    }

    float bi[4];
#pragma unroll
    for (int nt = 0; nt < 4; nt++) bi[nt] = bias[n0 + wn * 64 + nt * 16 + n_];
#pragma unroll
    for (int mt = 0; mt < 4; mt++)
#pragma unroll
        for (int reg = 0; reg < 4; reg++) {
            const int m = m0 + wm * 64 + mt * 16 + quad * 4 + reg;
#pragma unroll
            for (int nt = 0; nt < 4; nt++) {
                const int col = n0 + wn * 64 + nt * 16 + n_;
                out[(size_t)m * D_MODEL + col] = f2bf((acc[mt][nt][reg] + bi[nt]) * es);
            }
        }
}

// ---------------------------------------------------------------------------
// MFMA GEMM (R9 version, kept verbatim for V and O projections).
// 128x128 tile, BK=128 (two 64-wide LDS banks per operand).
// MODE 1: bf16 row-major; MODE 2: bf16 V^T packed; MODE 3: fp32 row-major.
// ---------------------------------------------------------------------------
template <typename TA, int MODE, typename TO>
__global__ __launch_bounds__(256, 2)
void mgemm_kernel(const TA *__restrict__ A,
                  const unsigned short *__restrict__ Wt,
                  const float *__restrict__ bias,
                  TO *__restrict__ out,
                  float escale)
{
    __shared__ __align__(16) unsigned short At[2][128 * 64];
    __shared__ __align__(16) unsigned short Bt[2][128 * 64];

    const int t = threadIdx.x;
    const int wave = t >> 6;
    const int lane = t & 63;
    const int n_ = lane & 15;
    const int quad = lane >> 4;
    const int wm = wave >> 1, wn = wave & 1;
    const int m0 = blockIdx.x * 128;
    const int n0 = blockIdx.y * 128;

    f32x4 acc[4][4];
#pragma unroll
    for (int i = 0; i < 4; i++)
#pragma unroll
        for (int j = 0; j < 4; j++) acc[i][j] = (f32x4){0.f, 0.f, 0.f, 0.f};

    const int srow = t >> 3; // (fallback) staging row
    const int sg = t & 7;    // (fallback) staging group
    const int rl = lane >> 3;        // gload sub-row 0..7
    const int gsw = (lane & 7) ^ rl; // gload inverse-swizzled col group

    for (int k0 = 0; k0 < D_MODEL; k0 += 128) {
        __syncthreads();
        if constexpr (sizeof(TA) == 2) {
            const unsigned short *Ab = (const unsigned short *)A;
#pragma unroll
            for (int h = 0; h < 2; h++)
#pragma unroll
                for (int c = 0; c < 4; c++) {
                    const int rb = wave * 32 + c * 8;
                    gload16(Ab + (size_t)(m0 + rb + rl) * D_MODEL + k0 + h * 64 + (gsw << 3),
                            &At[h][rb * 64]);
                    gload16(Wt + (size_t)(n0 + rb + rl) * D_MODEL + k0 + h * 64 + (gsw << 3),
                            &Bt[h][rb * 64]);
                }
        } else {
#pragma unroll
            for (int h = 0; h < 2; h++) {
#pragma unroll
                for (int i = 0; i < 4; i++) {
                    const int r = srow + 32 * i;
                    const float *p =
                        (const float *)A + (size_t)(m0 + r) * D_MODEL + k0 + h * 64 + sg * 8;
                    float4 lo = *(const float4 *)p;
                    float4 hi = *(const float4 *)(p + 4);
                    U4 pk;
                    pk.x = pack_trunc2(lo.x, lo.y);
                    pk.y = pack_trunc2(lo.z, lo.w);
                    pk.z = pack_trunc2(hi.x, hi.y);
                    pk.w = pack_trunc2(hi.z, hi.w);
                    *(U4 *)&At[h][sw_off(r, sg)] = pk;
                }
#pragma unroll
                for (int i = 0; i < 4; i++) {
                    const int r = srow + 32 * i;
                    const unsigned short *p =
                        Wt + (size_t)(n0 + r) * D_MODEL + k0 + h * 64 + sg * 8;
                    *(U4 *)&Bt[h][sw_off(r, sg)] = *(const U4 *)p;
                }
            }
        }
        __syncthreads();

#pragma unroll
        for (int c = 0; c < 4; c++) {
            const int bk_ = c >> 1, cc = c & 1;
            short8v af[4], bf[4];
#pragma unroll
            for (int mt = 0; mt < 4; mt++)
                af[mt] = *(const short8v *)&At[bk_][sw_off(wm * 64 + mt * 16 + n_, cc * 4 + quad)];
#pragma unroll
            for (int nt = 0; nt < 4; nt++)
                bf[nt] = *(const short8v *)&Bt[bk_][sw_off(wn * 64 + nt * 16 + n_, cc * 4 + quad)];
#pragma unroll
            for (int mt = 0; mt < 4; mt++)
#pragma unroll
                for (int nt = 0; nt < 4; nt++)
                    acc[mt][nt] = __builtin_amdgcn_mfma_f32_16x16x32_bf16(
                        af[mt], bf[nt], acc[mt][nt], 0, 0, 0);
        }
    }

    // ---- epilogue ----
    float bi[4];
#pragma unroll
    for (int nt = 0; nt < 4; nt++) bi[nt] = bias[n0 + wn * 64 + nt * 16 + n_];

    if constexpr (MODE == 2) {
#pragma unroll
        for (int mt = 0; mt < 4; mt++) {
            const int m = m0 + wm * 64 + mt * 16 + quad * 4;
#pragma unroll
            for (int nt = 0; nt < 4; nt++) {
                const int col = n0 + wn * 64 + nt * 16 + n_;
                const size_t idx = ((size_t)(m >> 11) * D_MODEL + col) * SEQ + (m & 2047);
                U2 pk;
                pk.x = pack_rne2(acc[mt][nt][0] + bi[nt], acc[mt][nt][1] + bi[nt]);
                pk.y = pack_rne2(acc[mt][nt][2] + bi[nt], acc[mt][nt][3] + bi[nt]);
                *(U2 *)((unsigned short *)out + idx) = pk;
            }
        }
    } else {
#pragma unroll
        for (int mt = 0; mt < 4; mt++)
#pragma unroll
            for (int reg = 0; reg < 4; reg++) {
                const int m = m0 + wm * 64 + mt * 16 + quad * 4 + reg;
#pragma unroll
                for (int nt = 0; nt < 4; nt++) {
                    const int col = n0 + wn * 64 + nt * 16 + n_;
                    const float v = (acc[mt][nt][reg] + bi[nt]) * escale;
                    if constexpr (MODE == 1)
                        ((unsigned short *)out)[(size_t)m * D_MODEL + col] = f2bf(v);
                    else
                        ((float *)out)[(size_t)m * D_MODEL + col] = v;
                }
            }
    }
}

// ---------------------------------------------------------------------------
// MFMA flash attention, 4-warp 32x32 swapped-QK^T, causally-paired Q-tiles.
// KVBLK=128: stage two 64-kv banks per barrier pair (halves barrier events,
// 34 -> 17 per block); compute halves sequentially (registers unchanged).
// ---------------------------------------------------------------------------
__global__ __launch_bounds__(256, 2)
void attn_kernel(const unsigned short *Qg,
                 const unsigned short *__restrict__ Kg,
                 const unsigned short *__restrict__ VTg,
                 unsigned short *AO)
{
    __shared__ __align__(16) unsigned short Kt[2][64 * 64];
    __shared__ __align__(16) unsigned short Vt[2][64 * 64];

    const int h = blockIdx.x;
    const int b = blockIdx.y;
    const int qpair = blockIdx.z;
    const int t = threadIdx.x;
    const int w = t >> 6; // 0..3
    const int lane = t & 63;
    const int ql = lane & 31; // q column within warp tile
    const int hi = lane >> 5; // lane half

    const size_t row_base = (size_t)b * SEQ * D_MODEL + h * HEAD_DIM;
    const size_t vhead = (size_t)(b * N_HEAD + h) * HEAD_DIM * SEQ;

    const int r0 = t >> 3; // staging row 0..31 (+32)
    const int g = t & 7;   // staging 8-elem group

#pragma unroll
    for (int pass = 0; pass < 2; ++pass) {
        const int qb = pass ? (15 - qpair) : qpair;
        const int qs0 = qb * 128 + w * 32;
        const int qseq = qs0 + ql;

        short8v qf[4];
#pragma unroll
        for (int c = 0; c < 4; c++)
            qf[c] = *(const short8v *)(Qg + row_base + (size_t)qseq * D_MODEL + c * 16 + hi * 8);

        float m_i = -INFINITY, l_i = 0.f;
        f32x16 Oacc[2];
#pragma unroll
        for (int dt = 0; dt < 2; dt++)
#pragma unroll
            for (int i = 0; i < 16; i++) Oacc[dt][i] = 0.f;

        const int nst = qb + 1; // 128-kv stages

        for (int s = 0; s <= nst - 1; ++s) {
            __syncthreads();
            // ---- stage 128 kv: K rows / V^T cols in two 64-banks ----
#pragma unroll
            for (int bk2 = 0; bk2 < 2; bk2++)
#pragma unroll
                for (int i = 0; i < 2; i++) {
                    const int r = r0 + 32 * i;
                    U4 kv = *(const U4 *)(Kg + row_base +
                                          (size_t)(s * 128 + bk2 * 64 + r) * D_MODEL + g * 8);
                    *(U4 *)&Kt[bk2][sw_off(r, g)] = kv;
                    U4 vv = *(const U4 *)(VTg + vhead + (size_t)r * SEQ + s * 128 + bk2 * 64 + g * 8);
                    *(U4 *)&Vt[bk2][sw_off(r, g)] = vv;
                }
            __syncthreads();

#pragma unroll
            for (int h2 = 0; h2 < 2; h2++) {
                const int kv0 = s * 128 + h2 * 64;
                if (kv0 > qs0 + 31) continue; // warp causally done for this half

                f32x16 st[2];
                __builtin_amdgcn_s_setprio(1);
#pragma unroll
                for (int kt = 0; kt < 2; kt++) {
#pragma unroll
                    for (int i = 0; i < 16; i++) st[kt][i] = 0.f;
#pragma unroll
                    for (int c = 0; c < 4; c++) {
                        short8v kf = *(const short8v *)&Kt[h2][sw_off(kt * 32 + ql, c * 2 + hi)];
                        st[kt] = __builtin_amdgcn_mfma_f32_32x32x16_bf16(kf, qf[c], st[kt], 0, 0, 0);
                    }
                }
                __builtin_amdgcn_s_setprio(0);

                if (kv0 + 63 > qs0) {
#pragma unroll
                    for (int kt = 0; kt < 2; kt++)
#pragma unroll
                        for (int r = 0; r < 16; r++) {
                            const int kseq = kv0 + kt * 32 + (r & 3) + 8 * (r >> 2) + 4 * hi;
                            if (kseq > qseq) st[kt][r] = -INFINITY;
                        }
                }

                float mx = -INFINITY;
#pragma unroll
                for (int kt = 0; kt < 2; kt++)
#pragma unroll
                    for (int r = 0; r < 16; r++) mx = fmaxf(mx, st[kt][r]);
                mx = fmaxf(mx, __shfl_xor(mx, 32, 64));
                const float mnew = fmaxf(m_i, mx);
                const float alpha = __builtin_amdgcn_exp2f(m_i - mnew);
                m_i = mnew;
                float rs = 0.f;
#pragma unroll
                for (int kt = 0; kt < 2; kt++)
#pragma unroll
                    for (int r = 0; r < 16; r++) {
                        const float p = __builtin_amdgcn_exp2f(st[kt][r] - mnew);
                        st[kt][r] = p;
                        rs += p;
                    }
                rs += __shfl_xor(rs, 32, 64);
                l_i = l_i * alpha + rs;
#pragma unroll
                for (int dt = 0; dt < 2; dt++)
#pragma unroll
                    for (int r = 0; r < 16; r++) Oacc[dt][r] *= alpha;

                short8v pf[4];
#pragma unroll
                for (int tt = 0; tt < 4; tt++) {
                    const int kt = tt >> 1, o = (tt & 1) * 8;
                    const uint32_t A  = pack_trunc2(st[kt][o + 0], st[kt][o + 1]);
                    const uint32_t A2 = pack_trunc2(st[kt][o + 2], st[kt][o + 3]);
                    const uint32_t B  = pack_trunc2(st[kt][o + 4], st[kt][o + 5]);
                    const uint32_t B2 = pack_trunc2(st[kt][o + 6], st[kt][o + 7]);
                    const uint32_t c1 = (uint32_t)__shfl_xor((int)(hi ? A : B), 32, 64);
                    const uint32_t c2 = (uint32_t)__shfl_xor((int)(hi ? A2 : B2), 32, 64);
                    union { uint32_t u[4]; short8v s; } cv;
                    cv.u[0] = hi ? c1 : A;
                    cv.u[1] = hi ? c2 : A2;
                    cv.u[2] = hi ? B : c1;
                    cv.u[3] = hi ? B2 : c2;
                    pf[tt] = cv.s;
                }

                __builtin_amdgcn_s_setprio(1);
#pragma unroll
                for (int dt = 0; dt < 2; dt++)
#pragma unroll
                    for (int tt = 0; tt < 4; tt++) {
                        short8v vf = *(const short8v *)&Vt[h2][sw_off(dt * 32 + ql, tt * 2 + hi)];
                        Oacc[dt] =
                            __builtin_amdgcn_mfma_f32_32x32x16_bf16(vf, pf[tt], Oacc[dt], 0, 0, 0);
                    }
                __builtin_amdgcn_s_setprio(0);
            }
        }

        const float linv = 1.f / l_i;
        const size_t obase = row_base + (size_t)qseq * D_MODEL;
#pragma unroll
        for (int dt = 0; dt < 2; dt++)
#pragma unroll
            for (int rg = 0; rg < 4; rg++) {
                const int d0 = dt * 32 + 8 * rg + 4 * hi;
                U2 pk;
                pk.x = (uint32_t)f2bf(Oacc[dt][4 * rg + 0] * linv) |
                       ((uint32_t)f2bf(Oacc[dt][4 * rg + 1] * linv) << 16);
                pk.y = (uint32_t)f2bf(Oacc[dt][4 * rg + 2] * linv) |
                       ((uint32_t)f2bf(Oacc[dt][4 * rg + 3] * linv) << 16);
                *(U2 *)(AO + obase + d0) = pk;
            }
    }
}

// ---------------------------------------------------------------------------
extern "C" void kernel_launch(void *const *d_in, const int *in_sizes, int n_in,
                              void *d_out, int out_size, void *d_ws, size_t ws_size,
                              hipStream_t stream)
{
    const float *q  = (const float *)d_in[0];
    const float *k  = (const float *)d_in[1];
    const float *v  = (const float *)d_in[2];
    const float *Wq = (const float *)d_in[3];
    const float *bq = (const float *)d_in[4];
    const float *Wk = (const float *)d_in[5];
    const float *bk = (const float *)d_in[6];
    const float *Wv = (const float *)d_in[7];
    const float *bv = (const float *)d_in[8];
    const float *Wo = (const float *)d_in[9];
    const float *bo = (const float *)d_in[10];
    float *out = (float *)d_out;

    const size_t TENS = (size_t)M_ROWS * D_MODEL;
    const size_t WT = (size_t)D_MODEL * D_MODEL;

    dim3 wgrid(32, 32);
    dim3 ggrid(M_ROWS / 128, D_MODEL / 128); // (64, 8)
    const int cgrid = (int)(TENS / 8 / 256); // 4096
    const float qscale = 0.03125f * 1.44269504088896341f;

    // bf16 path ws: qbuf kbuf vtbuf cq (4xTENS) + wt2 (2xWT) = 71.3 MB.
    // ck lives in d_out (16.78 MB of 33.55; dead before final O-GEMM writes).
    const size_t need_new = (4 * TENS + 2 * WT) * sizeof(unsigned short);

    if (ws_size >= need_new && (size_t)out_size >= TENS * sizeof(unsigned short)) {
        unsigned short *qbuf = (unsigned short *)d_ws;   // AO aliases this
        unsigned short *kbuf = qbuf + TENS;
        unsigned short *vtbuf = kbuf + TENS;
        unsigned short *cq = vtbuf + TENS;               // also reused for cv
        unsigned short *wt2 = cq + TENS;                 // [2][1024][1024]
        unsigned short *ck = (unsigned short *)d_out;

        wtrans_kernel<<<wgrid, 256, 0, stream>>>(Wq, wt2);
        wtrans_kernel<<<wgrid, 256, 0, stream>>>(Wk, wt2 + WT);
        cvt_kernel<<<cgrid, 256, 0, stream>>>(q, cq);
        cvt_kernel<<<cgrid, 256, 0, stream>>>(k, ck);
        qk_gemm_kernel<<<dim3(M_ROWS / 128, D_MODEL / 128, 2), 256, 0, stream>>>(
            cq, ck, wt2, bq, bk, qbuf, kbuf, qscale);

        wtrans_kernel<<<wgrid, 256, 0, stream>>>(Wv, wt2); // wt2[0] free after qk_gemm
        cvt_kernel<<<cgrid, 256, 0, stream>>>(v, cq);      // cq free after qk_gemm
        mgemm_kernel<unsigned short, 2, unsigned short><<<ggrid, 256, 0, stream>>>(
            cq, wt2, bv, vtbuf, 1.f);

        attn_kernel<<<dim3(N_HEAD, BATCH, SEQ / 256), 256, 0, stream>>>(qbuf, kbuf, vtbuf, qbuf);

        wtrans_kernel<<<wgrid, 256, 0, stream>>>(Wo, wt2);
        mgemm_kernel<unsigned short, 3, float><<<ggrid, 256, 0, stream>>>(qbuf, wt2, bo, out, 1.f);
    } else {
        // ---- fallback: fp32-staged path ----
        unsigned short *qbuf = (unsigned short *)d_ws;
        unsigned short *kbuf = qbuf + TENS;
        unsigned short *vtbuf = kbuf + TENS;
        unsigned short *wt = vtbuf + TENS;

        wtrans_kernel<<<wgrid, 256, 0, stream>>>(Wq, wt);
        mgemm_kernel<float, 1, unsigned short><<<ggrid, 256, 0, stream>>>(q, wt, bq, qbuf, qscale);
        wtrans_kernel<<<wgrid, 256, 0, stream>>>(Wk, wt);
        mgemm_kernel<float, 1, unsigned short><<<ggrid, 256, 0, stream>>>(k, wt, bk, kbuf, 1.f);
        wtrans_kernel<<<wgrid, 256, 0, stream>>>(Wv, wt);
        mgemm_kernel<float, 2, unsigned short><<<ggrid, 256, 0, stream>>>(v, wt, bv, vtbuf, 1.f);

        attn_kernel<<<dim3(N_HEAD, BATCH, SEQ / 256), 256, 0, stream>>>(qbuf, kbuf, vtbuf, qbuf);

        wtrans_kernel<<<wgrid, 256, 0, stream>>>(Wo, wt);
        mgemm_kernel<unsigned short, 3, float><<<ggrid, 256, 0, stream>>>(qbuf, wt, bo, out, 1.f);
    }
}

// Round 11
// 316.974 us; speedup vs baseline: 1.0156x; 1.0156x over previous
//
#include <hip/hip_runtime.h>
#include <hip/hip_bf16.h>
#include <cstdint>
#include <cstddef>

#define D_MODEL 1024
#define N_HEAD 16
#define HEAD_DIM 64
#define BATCH 4
#define SEQ 2048
#define M_ROWS (BATCH * SEQ) // 8192

typedef __attribute__((ext_vector_type(8))) short short8v;  // 8 bf16 (4 VGPRs)
typedef __attribute__((ext_vector_type(4))) float f32x4;    // MFMA 16x16 C/D
typedef __attribute__((ext_vector_type(16))) float f32x16;  // MFMA 32x32 C/D

// ---------- bf16 helpers ----------
__device__ __forceinline__ unsigned short f2bf(float f) { // RNE
    union { uint32_t i; float f; } c;
    c.f = f;
    uint32_t r = c.i + 0x7FFFu + ((c.i >> 16) & 1u);
    return (unsigned short)(r >> 16);
}
__device__ __forceinline__ unsigned short trunc_bf(float f) { // truncation
    return (unsigned short)(__float_as_uint(f) >> 16);
}
// pack hi16 of two fp32 into one dword: lo<-a, hi<-b (truncation)
__device__ __forceinline__ uint32_t pack_trunc2(float a, float b) {
    return __builtin_amdgcn_perm(__float_as_uint(b), __float_as_uint(a), 0x07060302u);
}
// pack two fp32 -> dword of 2 bf16 with RNE
__device__ __forceinline__ uint32_t pack_rne2(float a, float b) {
    return (uint32_t)f2bf(a) | ((uint32_t)f2bf(b) << 16);
}

struct __align__(16) U4 { uint32_t x, y, z, w; };
struct __align__(8) U2 { uint32_t x, y; };

// swizzled LDS offset (elements) within a 64-wide bank:
// row*64 + (8-elem group XOR low row bits)*8
__device__ __forceinline__ int sw_off(int row, int gl) {
    return row * 64 + ((gl ^ (row & 7)) << 3);
}

// async global->LDS, 16B per lane; LDS dest = wave-uniform base + lane*16
__device__ __forceinline__ void gload16(const unsigned short *g, unsigned short *l) {
    __builtin_amdgcn_global_load_lds((const __attribute__((address_space(1))) void *)g,
                                     (__attribute__((address_space(3))) void *)l, 16, 0, 0);
}

// ---------------------------------------------------------------------------
// PREP (single dispatch): blocks [0,4096) transpose the 4 weights
// (1024 blocks each, 32x32 tiles); blocks [4096,16384) convert q/k/v
// fp32->bf16 (4096 blocks per tensor). Collapses 7 launches into 1.
// ---------------------------------------------------------------------------
__global__ __launch_bounds__(256)
void prep_kernel(const float *__restrict__ Wq, const float *__restrict__ Wk,
                 const float *__restrict__ Wv, const float *__restrict__ Wo,
                 unsigned short *__restrict__ wt4,
                 const float *__restrict__ q, const float *__restrict__ k,
                 const float *__restrict__ v,
                 unsigned short *__restrict__ cq, unsigned short *__restrict__ ck,
                 unsigned short *__restrict__ cv)
{
    __shared__ float tile[32][33];
    const int id = blockIdx.x;
    const int t = threadIdx.x;
    if (id < 4096) {
        const int w = id >> 10; // weight index 0..3
        const int bx = id & 31, by = (id >> 5) & 31;
        const float *W = w == 0 ? Wq : (w == 1 ? Wk : (w == 2 ? Wv : Wo));
        unsigned short *Wt = wt4 + (size_t)w * D_MODEL * D_MODEL;
        const int tx = t & 31, ty = t >> 5; // ty 0..7
        const int bk = by * 32, bn = bx * 32;
#pragma unroll
        for (int i = 0; i < 4; i++)
            tile[ty + 8 * i][tx] = W[(size_t)(bk + ty + 8 * i) * D_MODEL + bn + tx];
        __syncthreads();
#pragma unroll
        for (int i = 0; i < 4; i++)
            Wt[(size_t)(bn + ty + 8 * i) * D_MODEL + bk + tx] = trunc_bf(tile[tx][ty + 8 * i]);
    } else {
        const int id2 = id - 4096;
        const int z = id2 >> 12; // tensor 0..2
        const int bx = id2 & 4095;
        const float *src = z == 0 ? q : (z == 1 ? k : v);
        unsigned short *dst = z == 0 ? cq : (z == 1 ? ck : cv);
        const size_t i = ((size_t)bx * 256 + t) * 8;
        float4 lo = *(const float4 *)(src + i);
        float4 hi = *(const float4 *)(src + i + 4);
        U4 pk;
        pk.x = pack_trunc2(lo.x, lo.y);
        pk.y = pack_trunc2(lo.z, lo.w);
        pk.z = pack_trunc2(hi.x, hi.y);
        pk.w = pack_trunc2(hi.z, hi.w);
        *(U4 *)(dst + i) = pk;
    }
}

// ---------------------------------------------------------------------------
// Weight transpose (fallback path only).
// ---------------------------------------------------------------------------
__global__ __launch_bounds__(256)
void wtrans_kernel(const float *__restrict__ W, unsigned short *__restrict__ Wt)
{
    __shared__ float tile[32][33];
    const int t = threadIdx.x;
    const int tx = t & 31, ty = t >> 5; // ty 0..7
    const int bk = blockIdx.y * 32, bn = blockIdx.x * 32;
#pragma unroll
    for (int i = 0; i < 4; i++)
        tile[ty + 8 * i][tx] = W[(size_t)(bk + ty + 8 * i) * D_MODEL + bn + tx];
    __syncthreads();
#pragma unroll
    for (int i = 0; i < 4; i++)
        Wt[(size_t)(bn + ty + 8 * i) * D_MODEL + bk + tx] = trunc_bf(tile[tx][ty + 8 * i]);
}

// ---------------------------------------------------------------------------
// Fused Q+K projection GEMM (R10 verbatim). blockIdx.z: 0 -> Q (escale), 1 -> K.
// ---------------------------------------------------------------------------
__global__ __launch_bounds__(256, 4)
void qk_gemm_kernel(const unsigned short *__restrict__ cq,
                    const unsigned short *__restrict__ ckb,
                    const unsigned short *__restrict__ wt2, // [2][1024][1024]
                    const float *__restrict__ bq, const float *__restrict__ bk,
                    unsigned short *__restrict__ oq, unsigned short *__restrict__ ok,
                    float qscale)
{
    __shared__ __align__(16) unsigned short At[128 * 64];
    __shared__ __align__(16) unsigned short Bt[128 * 64];

    const int z = blockIdx.z;
    const unsigned short *A = z ? ckb : cq;
    const unsigned short *Wt = wt2 + (size_t)z * D_MODEL * D_MODEL;
    const float *bias = z ? bk : bq;
    unsigned short *out = z ? ok : oq;
    const float es = z ? 1.f : qscale;

    const int t = threadIdx.x;
    const int wave = t >> 6;
    const int lane = t & 63;
    const int n_ = lane & 15;
    const int quad = lane >> 4;
    const int wm = wave >> 1, wn = wave & 1;
    const int m0 = blockIdx.x * 128;
    const int n0 = blockIdx.y * 128;

    f32x4 acc[4][4];
#pragma unroll
    for (int i = 0; i < 4; i++)
#pragma unroll
        for (int j = 0; j < 4; j++) acc[i][j] = (f32x4){0.f, 0.f, 0.f, 0.f};

    const int rl = lane >> 3;        // gload sub-row 0..7
    const int gsw = (lane & 7) ^ rl; // gload inverse-swizzled col group

    for (int k0 = 0; k0 < D_MODEL; k0 += 64) {
        __syncthreads();
#pragma unroll
        for (int c = 0; c < 4; c++) {
            const int rb = wave * 32 + c * 8;
            gload16(A + (size_t)(m0 + rb + rl) * D_MODEL + k0 + (gsw << 3), &At[rb * 64]);
            gload16(Wt + (size_t)(n0 + rb + rl) * D_MODEL + k0 + (gsw << 3), &Bt[rb * 64]);
        }
        __syncthreads();

#pragma unroll
        for (int c = 0; c < 2; c++) {
            short8v af[4], bf[4];
#pragma unroll
            for (int mt = 0; mt < 4; mt++)
                af[mt] = *(const short8v *)&At[sw_off(wm * 64 + mt * 16 + n_, c * 4 + quad)];
#pragma unroll
            for (int nt = 0; nt < 4; nt++)
                bf[nt] = *(const short8v *)&Bt[sw_off(wn * 64 + nt * 16 + n_, c * 4 + quad)];
#pragma unroll
            for (int mt = 0; mt < 4; mt++)
#pragma unroll
                for (int nt = 0; nt < 4; nt++)
                    acc[mt][nt] = __builtin_amdgcn_mfma_f32_16x16x32_bf16(
                        af[mt], bf[nt], acc[mt][nt], 0, 0, 0);
        }
    }

    float bi[4];
#pragma unroll
    for (int nt = 0; nt < 4; nt++) bi[nt] = bias[n0 + wn * 64 + nt * 16 + n_];
#pragma unroll
    for (int mt = 0; mt < 4; mt++)
#pragma unroll
        for (int reg = 0; reg < 4; reg++) {
            const int m = m0 + wm * 64 + mt * 16 + quad * 4 + reg;
#pragma unroll
            for (int nt = 0; nt < 4; nt++) {
                const int col = n0 + wn * 64 + nt * 16 + n_;
                out[(size_t)m * D_MODEL + col] = f2bf((acc[mt][nt][reg] + bi[nt]) * es);
            }
        }
}

// ---------------------------------------------------------------------------
// MFMA GEMM (R9/R10 verbatim; V and O projections + fp32 fallback).
// 128x128 tile, BK=128 (two 64-wide LDS banks per operand).
// MODE 1: bf16 row-major; MODE 2: bf16 V^T packed; MODE 3: fp32 row-major.
// ---------------------------------------------------------------------------
template <typename TA, int MODE, typename TO>
__global__ __launch_bounds__(256, 2)
void mgemm_kernel(const TA *__restrict__ A,
                  const unsigned short *__restrict__ Wt,
                  const float *__restrict__ bias,
                  TO *__restrict__ out,
                  float escale)
{
    __shared__ __align__(16) unsigned short At[2][128 * 64];
    __shared__ __align__(16) unsigned short Bt[2][128 * 64];

    const int t = threadIdx.x;
    const int wave = t >> 6;
    const int lane = t & 63;
    const int n_ = lane & 15;
    const int quad = lane >> 4;
    const int wm = wave >> 1, wn = wave & 1;
    const int m0 = blockIdx.x * 128;
    const int n0 = blockIdx.y * 128;

    f32x4 acc[4][4];
#pragma unroll
    for (int i = 0; i < 4; i++)
#pragma unroll
        for (int j = 0; j < 4; j++) acc[i][j] = (f32x4){0.f, 0.f, 0.f, 0.f};

    const int srow = t >> 3; // (fallback) staging row
    const int sg = t & 7;    // (fallback) staging group
    const int rl = lane >> 3;        // gload sub-row 0..7
    const int gsw = (lane & 7) ^ rl; // gload inverse-swizzled col group

    for (int k0 = 0; k0 < D_MODEL; k0 += 128) {
        __syncthreads();
        if constexpr (sizeof(TA) == 2) {
            const unsigned short *Ab = (const unsigned short *)A;
#pragma unroll
            for (int h = 0; h < 2; h++)
#pragma unroll
                for (int c = 0; c < 4; c++) {
                    const int rb = wave * 32 + c * 8;
                    gload16(Ab + (size_t)(m0 + rb + rl) * D_MODEL + k0 + h * 64 + (gsw << 3),
                            &At[h][rb * 64]);
                    gload16(Wt + (size_t)(n0 + rb + rl) * D_MODEL + k0 + h * 64 + (gsw << 3),
                            &Bt[h][rb * 64]);
                }
        } else {
#pragma unroll
            for (int h = 0; h < 2; h++) {
#pragma unroll
                for (int i = 0; i < 4; i++) {
                    const int r = srow + 32 * i;
                    const float *p =
                        (const float *)A + (size_t)(m0 + r) * D_MODEL + k0 + h * 64 + sg * 8;
                    float4 lo = *(const float4 *)p;
                    float4 hi = *(const float4 *)(p + 4);
                    U4 pk;
                    pk.x = pack_trunc2(lo.x, lo.y);
                    pk.y = pack_trunc2(lo.z, lo.w);
                    pk.z = pack_trunc2(hi.x, hi.y);
                    pk.w = pack_trunc2(hi.z, hi.w);
                    *(U4 *)&At[h][sw_off(r, sg)] = pk;
                }
#pragma unroll
                for (int i = 0; i < 4; i++) {
                    const int r = srow + 32 * i;
                    const unsigned short *p =
                        Wt + (size_t)(n0 + r) * D_MODEL + k0 + h * 64 + sg * 8;
                    *(U4 *)&Bt[h][sw_off(r, sg)] = *(const U4 *)p;
                }
            }
        }
        __syncthreads();

#pragma unroll
        for (int c = 0; c < 4; c++) {
            const int bk_ = c >> 1, cc = c & 1;
            short8v af[4], bf[4];
#pragma unroll
            for (int mt = 0; mt < 4; mt++)
                af[mt] = *(const short8v *)&At[bk_][sw_off(wm * 64 + mt * 16 + n_, cc * 4 + quad)];
#pragma unroll
            for (int nt = 0; nt < 4; nt++)
                bf[nt] = *(const short8v *)&Bt[bk_][sw_off(wn * 64 + nt * 16 + n_, cc * 4 + quad)];
#pragma unroll
            for (int mt = 0; mt < 4; mt++)
#pragma unroll
                for (int nt = 0; nt < 4; nt++)
                    acc[mt][nt] = __builtin_amdgcn_mfma_f32_16x16x32_bf16(
                        af[mt], bf[nt], acc[mt][nt], 0, 0, 0);
        }
    }

    // ---- epilogue ----
    float bi[4];
#pragma unroll
    for (int nt = 0; nt < 4; nt++) bi[nt] = bias[n0 + wn * 64 + nt * 16 + n_];

    if constexpr (MODE == 2) {
#pragma unroll
        for (int mt = 0; mt < 4; mt++) {
            const int m = m0 + wm * 64 + mt * 16 + quad * 4;
#pragma unroll
            for (int nt = 0; nt < 4; nt++) {
                const int col = n0 + wn * 64 + nt * 16 + n_;
                const size_t idx = ((size_t)(m >> 11) * D_MODEL + col) * SEQ + (m & 2047);
                U2 pk;
                pk.x = pack_rne2(acc[mt][nt][0] + bi[nt], acc[mt][nt][1] + bi[nt]);
                pk.y = pack_rne2(acc[mt][nt][2] + bi[nt], acc[mt][nt][3] + bi[nt]);
                *(U2 *)((unsigned short *)out + idx) = pk;
            }
        }
    } else {
#pragma unroll
        for (int mt = 0; mt < 4; mt++)
#pragma unroll
            for (int reg = 0; reg < 4; reg++) {
                const int m = m0 + wm * 64 + mt * 16 + quad * 4 + reg;
#pragma unroll
                for (int nt = 0; nt < 4; nt++) {
                    const int col = n0 + wn * 64 + nt * 16 + n_;
                    const float v = (acc[mt][nt][reg] + bi[nt]) * escale;
                    if constexpr (MODE == 1)
                        ((unsigned short *)out)[(size_t)m * D_MODEL + col] = f2bf(v);
                    else
                        ((float *)out)[(size_t)m * D_MODEL + col] = v;
                }
            }
    }
}

// ---------------------------------------------------------------------------
// MFMA flash attention (R6-exact: KVBLK=64, measured 69.3-73.2 us).
// 4-warp 32x32 swapped-QK^T, causally-paired Q-tiles.
// ---------------------------------------------------------------------------
__global__ __launch_bounds__(256, 2)
void attn_kernel(const unsigned short *Qg,
                 const unsigned short *__restrict__ Kg,
                 const unsigned short *__restrict__ VTg,
                 unsigned short *AO)
{
    __shared__ __align__(16) unsigned short Kt[64 * 64];
    __shared__ __align__(16) unsigned short Vt[64 * 64];

    const int h = blockIdx.x;
    const int b = blockIdx.y;
    const int qpair = blockIdx.z;
    const int t = threadIdx.x;
    const int w = t >> 6; // 0..3
    const int lane = t & 63;
    const int ql = lane & 31; // q column within warp tile
    const int hi = lane >> 5; // lane half

    const size_t row_base = (size_t)b * SEQ * D_MODEL + h * HEAD_DIM;
    const size_t vhead = (size_t)(b * N_HEAD + h) * HEAD_DIM * SEQ;

    const int r0 = t >> 3;
    const int g = t & 7;

#pragma unroll
    for (int pass = 0; pass < 2; ++pass) {
        const int qb = pass ? (15 - qpair) : qpair;
        const int qs0 = qb * 128 + w * 32;
        const int qseq = qs0 + ql;

        short8v qf[4];
#pragma unroll
        for (int c = 0; c < 4; c++)
            qf[c] = *(const short8v *)(Qg + row_base + (size_t)qseq * D_MODEL + c * 16 + hi * 8);

        float m_i = -INFINITY, l_i = 0.f;
        f32x16 Oacc[2];
#pragma unroll
        for (int dt = 0; dt < 2; dt++)
#pragma unroll
            for (int i = 0; i < 16; i++) Oacc[dt][i] = 0.f;

        const int kb_max = 2 * qb + 1;

        for (int kb = 0; kb <= kb_max; ++kb) {
            __syncthreads();
#pragma unroll
            for (int i = 0; i < 2; i++) {
                const int r = r0 + 32 * i;
                U4 kv = *(const U4 *)(Kg + row_base + (size_t)(kb * 64 + r) * D_MODEL + g * 8);
                *(U4 *)&Kt[sw_off(r, g)] = kv;
                U4 vv = *(const U4 *)(VTg + vhead + (size_t)r * SEQ + kb * 64 + g * 8);
                *(U4 *)&Vt[sw_off(r, g)] = vv;
            }
            __syncthreads();

            if (kb * 64 > qs0 + 31) continue;

            f32x16 st[2];
            __builtin_amdgcn_s_setprio(1);
#pragma unroll
            for (int kt = 0; kt < 2; kt++) {
#pragma unroll
                for (int i = 0; i < 16; i++) st[kt][i] = 0.f;
#pragma unroll
                for (int c = 0; c < 4; c++) {
                    short8v kf = *(const short8v *)&Kt[sw_off(kt * 32 + ql, c * 2 + hi)];
                    st[kt] = __builtin_amdgcn_mfma_f32_32x32x16_bf16(kf, qf[c], st[kt], 0, 0, 0);
                }
            }
            __builtin_amdgcn_s_setprio(0);

            if (kb * 64 + 63 > qs0) {
#pragma unroll
                for (int kt = 0; kt < 2; kt++)
#pragma unroll
                    for (int r = 0; r < 16; r++) {
                        const int kseq = kb * 64 + kt * 32 + (r & 3) + 8 * (r >> 2) + 4 * hi;
                        if (kseq > qseq) st[kt][r] = -INFINITY;
                    }
            }

            float mx = -INFINITY;
#pragma unroll
            for (int kt = 0; kt < 2; kt++)
#pragma unroll
                for (int r = 0; r < 16; r++) mx = fmaxf(mx, st[kt][r]);
            mx = fmaxf(mx, __shfl_xor(mx, 32, 64));
            const float mnew = fmaxf(m_i, mx);
            const float alpha = __builtin_amdgcn_exp2f(m_i - mnew);
            m_i = mnew;
            float rs = 0.f;
#pragma unroll
            for (int kt = 0; kt < 2; kt++)
#pragma unroll
                for (int r = 0; r < 16; r++) {
                    const float p = __builtin_amdgcn_exp2f(st[kt][r] - mnew);
                    st[kt][r] = p;
                    rs += p;
                }
            rs += __shfl_xor(rs, 32, 64);
            l_i = l_i * alpha + rs;
#pragma unroll
            for (int dt = 0; dt < 2; dt++)
#pragma unroll
                for (int r = 0; r < 16; r++) Oacc[dt][r] *= alpha;

            short8v pf[4];
#pragma unroll
            for (int tt = 0; tt < 4; tt++) {
                const int kt = tt >> 1, o = (tt & 1) * 8;
                const uint32_t A  = pack_trunc2(st[kt][o + 0], st[kt][o + 1]);
                const uint32_t A2 = pack_trunc2(st[kt][o + 2], st[kt][o + 3]);
                const uint32_t B  = pack_trunc2(st[kt][o + 4], st[kt][o + 5]);
                const uint32_t B2 = pack_trunc2(st[kt][o + 6], st[kt][o + 7]);
                const uint32_t c1 = (uint32_t)__shfl_xor((int)(hi ? A : B), 32, 64);
                const uint32_t c2 = (uint32_t)__shfl_xor((int)(hi ? A2 : B2), 32, 64);
                union { uint32_t u[4]; short8v s; } cv;
                cv.u[0] = hi ? c1 : A;
                cv.u[1] = hi ? c2 : A2;
                cv.u[2] = hi ? B : c1;
                cv.u[3] = hi ? B2 : c2;
                pf[tt] = cv.s;
            }

            __builtin_amdgcn_s_setprio(1);
#pragma unroll
            for (int dt = 0; dt < 2; dt++)
#pragma unroll
                for (int tt = 0; tt < 4; tt++) {
                    short8v vf = *(const short8v *)&Vt[sw_off(dt * 32 + ql, tt * 2 + hi)];
                    Oacc[dt] = __builtin_amdgcn_mfma_f32_32x32x16_bf16(vf, pf[tt], Oacc[dt], 0, 0, 0);
                }
            __builtin_amdgcn_s_setprio(0);
        }

        const float linv = 1.f / l_i;
        const size_t obase = row_base + (size_t)qseq * D_MODEL;
#pragma unroll
        for (int dt = 0; dt < 2; dt++)
#pragma unroll
            for (int rg = 0; rg < 4; rg++) {
                const int d0 = dt * 32 + 8 * rg + 4 * hi;
                U2 pk;
                pk.x = (uint32_t)f2bf(Oacc[dt][4 * rg + 0] * linv) |
                       ((uint32_t)f2bf(Oacc[dt][4 * rg + 1] * linv) << 16);
                pk.y = (uint32_t)f2bf(Oacc[dt][4 * rg + 2] * linv) |
                       ((uint32_t)f2bf(Oacc[dt][4 * rg + 3] * linv) << 16);
                *(U2 *)(AO + obase + d0) = pk;
            }
    }
}

// ---------------------------------------------------------------------------
extern "C" void kernel_launch(void *const *d_in, const int *in_sizes, int n_in,
                              void *d_out, int out_size, void *d_ws, size_t ws_size,
                              hipStream_t stream)
{
    const float *q  = (const float *)d_in[0];
    const float *k  = (const float *)d_in[1];
    const float *v  = (const float *)d_in[2];
    const float *Wq = (const float *)d_in[3];
    const float *bq = (const float *)d_in[4];
    const float *Wk = (const float *)d_in[5];
    const float *bk = (const float *)d_in[6];
    const float *Wv = (const float *)d_in[7];
    const float *bv = (const float *)d_in[8];
    const float *Wo = (const float *)d_in[9];
    const float *bo = (const float *)d_in[10];
    float *out = (float *)d_out;

    const size_t TENS = (size_t)M_ROWS * D_MODEL;
    const size_t WT = (size_t)D_MODEL * D_MODEL;

    dim3 wgrid(32, 32);
    dim3 ggrid(M_ROWS / 128, D_MODEL / 128); // (64, 8)
    const float qscale = 0.03125f * 1.44269504088896341f;

    // bf16 path ws: qbuf kbuf vtbuf cq (4xTENS) + wt4 (4xWT) = 75.5 MB.
    // ck + cv live in d_out (2xTENS bf16 = 33.55 MB = out_size exactly);
    // both dead before the final O-GEMM writes out.
    const size_t need_new = (4 * TENS + 4 * WT) * sizeof(unsigned short);

    if (ws_size >= need_new && (size_t)out_size >= 2 * TENS * sizeof(unsigned short)) {
        unsigned short *qbuf = (unsigned short *)d_ws;   // AO aliases this
        unsigned short *kbuf = qbuf + TENS;
        unsigned short *vtbuf = kbuf + TENS;
        unsigned short *cq = vtbuf + TENS;
        unsigned short *wt4 = cq + TENS;                 // [4][1024][1024]
        unsigned short *ck = (unsigned short *)d_out;
        unsigned short *cv = ck + TENS;

        // 1: all weight transposes + all activations converts, one dispatch
        prep_kernel<<<16384, 256, 0, stream>>>(Wq, Wk, Wv, Wo, wt4, q, k, v, cq, ck, cv);
        // 2: fused Q+K projections
        qk_gemm_kernel<<<dim3(M_ROWS / 128, D_MODEL / 128, 2), 256, 0, stream>>>(
            cq, ck, wt4, bq, bk, qbuf, kbuf, qscale);
        // 3: V projection (V^T layout)
        mgemm_kernel<unsigned short, 2, unsigned short><<<ggrid, 256, 0, stream>>>(
            cv, wt4 + 2 * WT, bv, vtbuf, 1.f);
        // 4: attention
        attn_kernel<<<dim3(N_HEAD, BATCH, SEQ / 256), 256, 0, stream>>>(qbuf, kbuf, vtbuf, qbuf);
        // 5: output projection
        mgemm_kernel<unsigned short, 3, float><<<ggrid, 256, 0, stream>>>(
            qbuf, wt4 + 3 * WT, bo, out, 1.f);
    } else {
        // ---- fallback: fp32-staged path ----
        unsigned short *qbuf = (unsigned short *)d_ws;
        unsigned short *kbuf = qbuf + TENS;
        unsigned short *vtbuf = kbuf + TENS;
        unsigned short *wt = vtbuf + TENS;

        wtrans_kernel<<<wgrid, 256, 0, stream>>>(Wq, wt);
        mgemm_kernel<float, 1, unsigned short><<<ggrid, 256, 0, stream>>>(q, wt, bq, qbuf, qscale);
        wtrans_kernel<<<wgrid, 256, 0, stream>>>(Wk, wt);
        mgemm_kernel<float, 1, unsigned short><<<ggrid, 256, 0, stream>>>(k, wt, bk, kbuf, 1.f);
        wtrans_kernel<<<wgrid, 256, 0, stream>>>(Wv, wt);
        mgemm_kernel<float, 2, unsigned short><<<ggrid, 256, 0, stream>>>(v, wt, bv, vtbuf, 1.f);

        attn_kernel<<<dim3(N_HEAD, BATCH, SEQ / 256), 256, 0, stream>>>(qbuf, kbuf, vtbuf, qbuf);

        wtrans_kernel<<<wgrid, 256, 0, stream>>>(Wo, wt);
        mgemm_kernel<unsigned short, 3, float><<<ggrid, 256, 0, stream>>>(qbuf, wt, bo, out, 1.f);
    }
}